// Round 10
// baseline (921.080 us; speedup 1.0000x reference)
//
#include <hip/hip_runtime.h>

#define DM     512
#define LAT    128
#define WIN_   256
#define ENC    55
#define GB     32        // batch groups
#define BT     8         // batch rows per group
#define DS     64        // h-dims per slice
#define TPB    768       // 12 waves
#define OUT_T  256
#define AROW16 528       // u16 per sm16 row (512 data + 16 pad)
#define GHS    200       // ghT row stride in floats
#define OWS    520       // sOutW row stride in u16
#define NK     22        // records per (row, slice): ceil(64/3)
#define NKP    24        // padded record slots

typedef __attribute__((ext_vector_type(8))) short bf8;
typedef __attribute__((ext_vector_type(4))) float f4;
typedef unsigned long long u64;
typedef unsigned short u16;

// .bss scratch: zero at load, not poisoned by the harness.
// Record u64 = [seq16 | bf16 d0 | bf16 d1 | bf16 d2] — single-copy atomic:
// seq and data always consistent. Producers fire-and-forget.
// Consumers spin on the records THEMSELVES (validating load = fetch, 1 RT)
// with s_sleep backoff so poll traffic stays ~12 lines/wave/64cyc (R8's
// regression was the same idea unthrottled).
__device__ __align__(128) u64 g_ring2[2][GB][8][BT][NKP];  // ~786 KB
__device__ __align__(128) u64 g_lcnt[GB * 8 * 16];         // per-(g,s) launch count

__device__ __forceinline__ u16 f2bf(float f) {
    union { float f; unsigned int i; } v; v.f = f;
    unsigned int r = v.i + 0x7fffu + ((v.i >> 16) & 1u);
    return (u16)(r >> 16);
}
__device__ __forceinline__ float sigm(float x) { return 1.f / (1.f + __expf(-x)); }
__device__ __forceinline__ float tanh_(float x) {
    x = fminf(x, 40.f);
    float e = __expf(2.f * x);
    return (e - 1.f) / (e + 1.f);
}
#define ALOAD(p)     __hip_atomic_load((p),      __ATOMIC_RELAXED, __HIP_MEMORY_SCOPE_AGENT)
#define ASTORE(p, v) __hip_atomic_store((p), (v), __ATOMIC_RELAXED, __HIP_MEMORY_SCOPE_AGENT)

// Persistent fused GRU+projection. 256 blocks = 32 batch-groups x 8 d-slices.
// Per step: waves 0-7 stage own slice + spin-fetch one remote slice (merged
// detect+fetch, s_sleep-throttled); all 12 waves gate GEMM (4 independent
// accumulators -> 4-deep MFMA chain) vs resident w_hh fragments; waves 0-7
// gate math (1 dim/lane) -> pack via LDS -> fire-and-forget publish;
// waves 8-11 projection vs LDS-resident bf16 out_w (1-in-8 steps per block).
// base = lc*512 + 1 (seq never 0 -> virgin .bss can't validate; no aliasing).
__global__ __launch_bounds__(TPB, 3) void gru_fused(
    const float* __restrict__ z,    // [256][128]
    const float* __restrict__ hpw,  // [512][128]
    const float* __restrict__ hpb,  // [512]
    const float* __restrict__ whh,  // [1536][512]
    const float* __restrict__ bih,  // [1536]
    const float* __restrict__ bhh,  // [1536]
    const float* __restrict__ outw, // [55][512]
    const float* __restrict__ outb, // [55]
    float* __restrict__ out)        // [256][256][55] fp32
{
    const int blk  = blockIdx.x;
    const int g    = blk & (GB - 1);
    const int s    = blk >> 5;
    const int d0   = s * DS;
    const int row0 = g * BT;
    const int tid  = threadIdx.x;
    const int wave = tid >> 6;
    const int lane = tid & 63;
    const int quad = lane >> 4;
    const int nl   = lane & 15;

    __shared__ __align__(16) u16 sm16[BT * AROW16];   // staged h(t-1) bf16
    __shared__ __align__(16) float ghT[BT][GHS];      // [batch][gate*64+dim]
    __shared__ float bias_r[DS], bias_z[DS], gin_[DS], bhn_[DS];
    __shared__ __align__(16) u16 hpack[BT][66];       // bf16 h(t) rows + pad
    __shared__ __align__(16) u16 sOutW[ENC * OWS];    // bf16 out_w, padded
    __shared__ float sOutB[64];
    __shared__ u64 sh_lc;

    u64* lc_own = g_lcnt + (u64)(g * 8 + s) * 16;
    if (tid == 0) sh_lc = ALOAD(lc_own);

    if (tid < DS) {
        int dg = d0 + tid;
        bias_r[tid] = bih[dg]       + bhh[dg];
        bias_z[tid] = bih[512 + dg] + bhh[512 + dg];
        gin_[tid]   = bih[1024 + dg];
        bhn_[tid]   = bhh[1024 + dg];
    }
    if (tid < ENC) sOutB[tid] = outb[tid];
    for (int i = tid; i < ENC * DM; i += TPB)
        sOutW[(i >> 9) * OWS + (i & 511)] = f2bf(outw[i]);

    // Resident w_hh B-fragments: this wave's 16 gate rows x K=512.
    const int gl   = wave * 16 + nl;
    const int sel  = gl >> 6;
    const int jrow = sel * 512 + d0 + (gl & 63);
    bf8 bfrag[16];
#pragma unroll
    for (int kb = 0; kb < 16; ++kb) {
        const float* wp = whh + jrow * DM + kb * 32 + quad * 8;
        bf8 v;
#pragma unroll
        for (int j = 0; j < 8; ++j) v[j] = (short)f2bf(wp[j]);
        bfrag[kb] = v;
    }
    __syncthreads();  // sh_lc, biases, sOutW ready

    const u64 base = sh_lc * 512ULL + 1ULL;   // seq never 0 (virgin .bss)
    float hprev_reg = 0.f;                    // waves 0-7: h[row=wave][dim=lane]

    // h0 = tanh(z @ hpw^T + hpb): wave w lane d computes its own element
    if (wave < BT) {
        float acc = hpb[d0 + lane];
        const float* zr = z + (row0 + wave) * LAT;
        const float* wr = hpw + (d0 + lane) * LAT;
#pragma unroll 8
        for (int k = 0; k < LAT; ++k) acc += zr[k] * wr[k];
        hprev_reg = tanh_(acc);
        if (lane < 2) hpack[wave][64 + lane] = 0;   // zero record pads once
        hpack[wave][lane] = f2bf(hprev_reg);
        const u16 sq = (u16)base;
        if (lane < NK) {
            u16 b0 = hpack[wave][3 * lane], b1 = hpack[wave][3 * lane + 1],
                b2 = hpack[wave][3 * lane + 2];
            u64 rec = (u64)sq | ((u64)b0 << 16) | ((u64)b1 << 32) | ((u64)b2 << 48);
            ASTORE(&g_ring2[0][g][s][wave][lane], rec);
        }
    }

    const u16* afrag_base = sm16 + (nl & 7) * AROW16;

    for (int t = 1; t <= WIN_; ++t) {
        const int sp = (t - 1) & 1, sc = t & 1;
        const u16 want = (u16)(base + t - 1);

        // ---- stage h(t-1) into sm16 ----
        if (wave < BT)
            sm16[wave * AROW16 + d0 + lane] = f2bf(hprev_reg);  // own slice
        if (wave >= 1 && wave < 8) {
            const int j = (s + wave) & 7;
            const u64* rb = &g_ring2[sp][g][j][0][0];
            const int row = lane >> 3, k = lane & 7;
            const u64* p0 = rb + row * NKP + k;
            const bool v2 = (k + 16) < NK;
            // merged detect+fetch: spin on the data itself, sleep-throttled
            u64 r0 = 0, r1 = 0, r2 = 0;
            bool ok0 = false, ok1 = false, ok2 = !v2;
            long guard = 0;
            for (;;) {
                if (!ok0) { r0 = ALOAD(p0);      ok0 = ((u16)r0 == want); }
                if (!ok1) { r1 = ALOAD(p0 + 8);  ok1 = ((u16)r1 == want); }
                if (!ok2) { r2 = ALOAD(p0 + 16); ok2 = ((u16)r2 == want); }
                if (__all(ok0 && ok1 && ok2) || ++guard > (1L << 18)) break;
                __builtin_amdgcn_s_sleep(1);   // ~64 cyc backoff (throttle)
            }
            u16* dst = sm16 + row * AROW16 + j * 64;
            int db = 3 * k;
            dst[db] = (u16)(r0 >> 16); dst[db + 1] = (u16)(r0 >> 32); dst[db + 2] = (u16)(r0 >> 48);
            db = 3 * (k + 8);
            dst[db] = (u16)(r1 >> 16); dst[db + 1] = (u16)(r1 >> 32); dst[db + 2] = (u16)(r1 >> 48);
            if (v2) {
                db = 3 * (k + 16);
                dst[db] = (u16)(r2 >> 16);
                if (db + 1 < DS) dst[db + 1] = (u16)(r2 >> 32);
                if (db + 2 < DS) dst[db + 2] = (u16)(r2 >> 48);
            }
        }
        __syncthreads();  // A: tile complete

        // ---- gate GEMM: 192 rows x K=512, 4 independent accumulators ----
        f4 a0 = {0,0,0,0}, a1 = {0,0,0,0}, a2 = {0,0,0,0}, a3 = {0,0,0,0};
#pragma unroll
        for (int kb = 0; kb < 4; ++kb) {
            a0 = __builtin_amdgcn_mfma_f32_16x16x32_bf16(
                 *(const bf8*)(afrag_base + quad * 8 + kb * 32),        bfrag[kb],      a0, 0, 0, 0);
            a1 = __builtin_amdgcn_mfma_f32_16x16x32_bf16(
                 *(const bf8*)(afrag_base + quad * 8 + (kb + 4) * 32),  bfrag[kb + 4],  a1, 0, 0, 0);
            a2 = __builtin_amdgcn_mfma_f32_16x16x32_bf16(
                 *(const bf8*)(afrag_base + quad * 8 + (kb + 8) * 32),  bfrag[kb + 8],  a2, 0, 0, 0);
            a3 = __builtin_amdgcn_mfma_f32_16x16x32_bf16(
                 *(const bf8*)(afrag_base + quad * 8 + (kb + 12) * 32), bfrag[kb + 12], a3, 0, 0, 0);
        }
        f4 acc = (a0 + a1) + (a2 + a3);
        if (quad < 2) {
#pragma unroll
            for (int r = 0; r < 4; ++r) ghT[quad * 4 + r][gl] = acc[r];
        }
        __syncthreads();  // B: ghT complete

        // ---- waves 0-7: gate update (1 dim/lane) + publish ----
        if (wave < BT) {
            const int d = lane;
            const float* grow = &ghT[wave][0];
            float rr = sigm(bias_r[d] + grow[d]);
            float zg = sigm(bias_z[d] + grow[64 + d]);
            float nn = tanh_(gin_[d] + rr * (bhn_[d] + grow[128 + d]));
            float h  = (1.f - zg) * nn + zg * hprev_reg;
            hprev_reg = h;
            hpack[wave][d] = f2bf(h);
            const u16 sq = (u16)(base + t);
            if (lane < NK) {   // same-wave LDS write->read: lgkmcnt-ordered
                u16 b0 = hpack[wave][3 * lane], b1 = hpack[wave][3 * lane + 1],
                    b2 = hpack[wave][3 * lane + 2];
                u64 rec = (u64)sq | ((u64)b0 << 16) | ((u64)b1 << 32) | ((u64)b2 << 48);
                ASTORE(&g_ring2[sc][g][s][wave][lane], rec);
            }
        }

        // ---- waves 8-11: projection out[:,tau,:] from sm16 (h(tau+1)=h(t-1)) ----
        const int tau = t - 2;
        const bool proj = (tau >= 0) && ((tau & 7) == s);
        if (proj && wave >= 8) {
            const int e  = (wave - 8) * 16 + nl;
            const int ec = (e < ENC) ? e : (ENC - 1);
            const u16* wrow = sOutW + ec * OWS + quad * 8;
            f4 accp = {0.f, 0.f, 0.f, 0.f};
#pragma unroll
            for (int kb = 0; kb < 16; ++kb) {
                bf8 av = *(const bf8*)(afrag_base + quad * 8 + kb * 32);
                bf8 wv = *(const bf8*)(wrow + kb * 32);
                accp = __builtin_amdgcn_mfma_f32_16x16x32_bf16(av, wv, accp, 0, 0, 0);
            }
            if (quad < 2 && e < ENC) {
                float ob = sOutB[e];
#pragma unroll
                for (int r = 0; r < 4; ++r) {
                    int m = quad * 4 + r;
                    out[(row0 + m) * (OUT_T * ENC) + tau * ENC + e] = accp[r] + ob;
                }
            }
        }
        if (proj) __syncthreads();  // C: protect sm16 before next stage overwrite
    }

    // ---- tail: tau=255 uses h(256) (slot 0, seq base+256); s==7 projects ----
    if (s == 7) {
        const u16 want = (u16)(base + WIN_);
        if (wave < BT)
            sm16[wave * AROW16 + d0 + lane] = f2bf(hprev_reg);
        if (wave >= 1 && wave < 8) {
            const int j = (s + wave) & 7;
            const u64* rb = &g_ring2[0][g][j][0][0];
            const int row = lane >> 3, k = lane & 7;
            const u64* p0 = rb + row * NKP + k;
            const bool v2 = (k + 16) < NK;
            u64 r0 = 0, r1 = 0, r2 = 0;
            bool ok0 = false, ok1 = false, ok2 = !v2;
            long guard = 0;
            for (;;) {
                if (!ok0) { r0 = ALOAD(p0);      ok0 = ((u16)r0 == want); }
                if (!ok1) { r1 = ALOAD(p0 + 8);  ok1 = ((u16)r1 == want); }
                if (!ok2) { r2 = ALOAD(p0 + 16); ok2 = ((u16)r2 == want); }
                if (__all(ok0 && ok1 && ok2) || ++guard > (1L << 18)) break;
                __builtin_amdgcn_s_sleep(1);
            }
            u16* dst = sm16 + row * AROW16 + j * 64;
            int db = 3 * k;
            dst[db] = (u16)(r0 >> 16); dst[db + 1] = (u16)(r0 >> 32); dst[db + 2] = (u16)(r0 >> 48);
            db = 3 * (k + 8);
            dst[db] = (u16)(r1 >> 16); dst[db + 1] = (u16)(r1 >> 32); dst[db + 2] = (u16)(r1 >> 48);
            if (v2) {
                db = 3 * (k + 16);
                dst[db] = (u16)(r2 >> 16);
                if (db + 1 < DS) dst[db + 1] = (u16)(r2 >> 32);
                if (db + 2 < DS) dst[db + 2] = (u16)(r2 >> 48);
            }
        }
        __syncthreads();
        if (wave >= 8) {
            const int e  = (wave - 8) * 16 + nl;
            const int ec = (e < ENC) ? e : (ENC - 1);
            const u16* wrow = sOutW + ec * OWS + quad * 8;
            f4 accp = {0.f, 0.f, 0.f, 0.f};
#pragma unroll
            for (int kb = 0; kb < 16; ++kb) {
                bf8 av = *(const bf8*)(afrag_base + quad * 8 + kb * 32);
                bf8 wv = *(const bf8*)(wrow + kb * 32);
                accp = __builtin_amdgcn_mfma_f32_16x16x32_bf16(av, wv, accp, 0, 0, 0);
            }
            if (quad < 2 && e < ENC) {
                float ob = sOutB[e];
#pragma unroll
                for (int r = 0; r < 4; ++r) {
                    int m = quad * 4 + r;
                    out[(row0 + m) * (OUT_T * ENC) + 255 * ENC + e] = accp[r] + ob;
                }
            }
        }
    }

    // bump own launch counter (next launch's base)
    if (tid == 0) ASTORE(lc_own, sh_lc + 1ULL);
}

extern "C" void kernel_launch(void* const* d_in, const int* in_sizes, int n_in,
                              void* d_out, int out_size, void* d_ws, size_t ws_size,
                              hipStream_t stream) {
    const float* z    = (const float*)d_in[0];
    const float* hpw  = (const float*)d_in[1];
    const float* hpb  = (const float*)d_in[2];
    // d_in[3] = w_ih: unused by the reference (input gates are pure biases)
    const float* whh  = (const float*)d_in[4];
    const float* bih  = (const float*)d_in[5];
    const float* bhh  = (const float*)d_in[6];
    const float* outw = (const float*)d_in[7];
    const float* outb = (const float*)d_in[8];
    float* out = (float*)d_out;

    (void)d_ws; (void)ws_size;  // scratch lives in module .bss
    gru_fused<<<dim3(256), dim3(TPB), 0, stream>>>(
        z, hpw, hpb, whh, bih, bhh, outw, outb, out);
}

// Round 12
// 750.349 us; speedup vs baseline: 1.2275x; 1.2275x over previous
//
#include <hip/hip_runtime.h>

#define DM     512
#define LAT    128
#define WIN_   256
#define ENC    55
#define GB     32        // batch groups
#define BT     8         // batch rows per group
#define DS     64        // h-dims per slice
#define TPB    768       // 12 waves
#define OUT_T  256
#define AROW16 528       // u16 per sm16 row (512 data + 16 pad)
#define GHS    200       // ghT row stride in floats
#define OWS    520       // sOutW row stride in u16
#define NK     22        // records per (row, slice): ceil(64/3)
#define NKP    24        // padded record slots

typedef __attribute__((ext_vector_type(8))) short bf8;
typedef __attribute__((ext_vector_type(4))) float f4;
typedef unsigned long long u64;
typedef unsigned short u16;

// .bss scratch: zero at load, not poisoned by the harness.
// Record u64 = [seq16 | bf16 d0 | bf16 d1 | bf16 d2] — aligned 8B load/store is
// single-copy atomic, so seq+data are always consistent. Producers
// fire-and-forget; consumers poll ONE broadcast line then fetch-once+validate.
// (R10: polling the payload floods the MALL; R11: sc0 "XCD-L2 scope" loads can
// hit stale L1 and spin forever — agent-scope atomics are the only safe path.)
__device__ __align__(128) u64 g_ring2[2][GB][8][BT][NKP];  // ~786 KB
__device__ __align__(128) u64 g_lcnt[GB * 8 * 16];         // per-(g,s) launch count

__device__ __forceinline__ u16 f2bf(float f) {
    union { float f; unsigned int i; } v; v.f = f;
    unsigned int r = v.i + 0x7fffu + ((v.i >> 16) & 1u);
    return (u16)(r >> 16);
}
__device__ __forceinline__ float sigm(float x) { return 1.f / (1.f + __expf(-x)); }
__device__ __forceinline__ float tanh_(float x) {
    x = fminf(x, 40.f);
    float e = __expf(2.f * x);
    return (e - 1.f) / (e + 1.f);
}
#define ALOAD(p)     __hip_atomic_load((p),      __ATOMIC_RELAXED, __HIP_MEMORY_SCOPE_AGENT)
#define ASTORE(p, v) __hip_atomic_store((p), (v), __ATOMIC_RELAXED, __HIP_MEMORY_SCOPE_AGENT)

// Persistent fused GRU+projection. 256 blocks = 32 batch-groups x 8 d-slices.
// Per step: waves 0-7 stage own slice + poll/fetch one remote slice; all 12
// waves gate GEMM (4 independent accumulators -> 4-deep MFMA chain) vs
// resident w_hh fragments; waves 0-7 gate math (1 dim/lane) -> pack via LDS ->
// fire-and-forget publish; waves 8-11 projection vs LDS-resident bf16 out_w
// (1-in-8 steps; sm16 double-buffer removes the protective barrier).
// base = lc*512 + 1 (seq never 0 -> virgin .bss can't validate; no aliasing).
__global__ __launch_bounds__(TPB, 3) void gru_fused(
    const float* __restrict__ z,    // [256][128]
    const float* __restrict__ hpw,  // [512][128]
    const float* __restrict__ hpb,  // [512]
    const float* __restrict__ whh,  // [1536][512]
    const float* __restrict__ bih,  // [1536]
    const float* __restrict__ bhh,  // [1536]
    const float* __restrict__ outw, // [55][512]
    const float* __restrict__ outb, // [55]
    float* __restrict__ out)        // [256][256][55] fp32
{
    const int blk  = blockIdx.x;
    const int g    = blk & (GB - 1);
    const int s    = blk >> 5;
    const int d0   = s * DS;
    const int row0 = g * BT;
    const int tid  = threadIdx.x;
    const int wave = tid >> 6;
    const int lane = tid & 63;
    const int quad = lane >> 4;
    const int nl   = lane & 15;

    __shared__ __align__(16) u16 sm16[2][BT * AROW16]; // staged h(t-1), dbuf
    __shared__ __align__(16) float ghT[BT][GHS];       // [batch][gate*64+dim]
    __shared__ float bias_r[DS], bias_z[DS], gin_[DS], bhn_[DS];
    __shared__ __align__(16) u16 hpack[BT][66];        // bf16 h(t) rows + pad
    __shared__ __align__(16) u16 sOutW[ENC * OWS];     // bf16 out_w, padded
    __shared__ float sOutB[64];
    __shared__ u64 sh_lc;

    u64* lc_own = g_lcnt + (u64)(g * 8 + s) * 16;
    if (tid == 0) sh_lc = ALOAD(lc_own);

    if (tid < DS) {
        int dg = d0 + tid;
        bias_r[tid] = bih[dg]       + bhh[dg];
        bias_z[tid] = bih[512 + dg] + bhh[512 + dg];
        gin_[tid]   = bih[1024 + dg];
        bhn_[tid]   = bhh[1024 + dg];
    }
    if (tid < ENC) sOutB[tid] = outb[tid];
    for (int i = tid; i < ENC * DM; i += TPB)
        sOutW[(i >> 9) * OWS + (i & 511)] = f2bf(outw[i]);

    // Resident w_hh B-fragments: this wave's 16 gate rows x K=512.
    const int gl   = wave * 16 + nl;
    const int sel  = gl >> 6;
    const int jrow = sel * 512 + d0 + (gl & 63);
    bf8 bfrag[16];
#pragma unroll
    for (int kb = 0; kb < 16; ++kb) {
        const float* wp = whh + jrow * DM + kb * 32 + quad * 8;
        bf8 v;
#pragma unroll
        for (int j = 0; j < 8; ++j) v[j] = (short)f2bf(wp[j]);
        bfrag[kb] = v;
    }
    __syncthreads();  // sh_lc, biases, sOutW ready

    const u64 base = sh_lc * 512ULL + 1ULL;   // seq never 0 (virgin .bss)
    float hprev_reg = 0.f;                    // waves 0-7: h[row=wave][dim=lane]

    // h0 = tanh(z @ hpw^T + hpb): wave w lane d computes its own element
    if (wave < BT) {
        float acc = hpb[d0 + lane];
        const float* zr = z + (row0 + wave) * LAT;
        const float* wr = hpw + (d0 + lane) * LAT;
#pragma unroll 8
        for (int k = 0; k < LAT; ++k) acc += zr[k] * wr[k];
        hprev_reg = tanh_(acc);
        if (lane < 2) hpack[wave][64 + lane] = 0;   // zero record pads once
        hpack[wave][lane] = f2bf(hprev_reg);
        const u16 sq = (u16)base;
        if (lane < NK) {   // same-wave LDS write->read: DS ops are in-order
            u16 b0 = hpack[wave][3 * lane], b1 = hpack[wave][3 * lane + 1],
                b2 = hpack[wave][3 * lane + 2];
            u64 rec = (u64)sq | ((u64)b0 << 16) | ((u64)b1 << 32) | ((u64)b2 << 48);
            ASTORE(&g_ring2[0][g][s][wave][lane], rec);
        }
    }

    for (int t = 1; t <= WIN_; ++t) {
        const int sp = (t - 1) & 1, sc = t & 1;
        const u16 want = (u16)(base + t - 1);
        u16* sm_t = sm16[t & 1];

        // ---- stage h(t-1) into sm_t ----
        if (wave < BT)
            sm_t[wave * AROW16 + d0 + lane] = f2bf(hprev_reg);  // own slice
        if (wave >= 1 && wave < 8) {
            const int j = (s + wave) & 7;
            const u64* rb = &g_ring2[sp][g][j][0][0];
            const int row = lane >> 3, k = lane & 7;
            // cheap poll: one broadcast address (a late-issued record)
            {
                const u64* pp = rb + 7 * NKP + 21;
                long guard = 0;
                while ((u16)ALOAD(pp) != want && guard < (1L << 18)) ++guard;
            }
            // fetch once + validate + retry stragglers
            const u64* p0 = rb + row * NKP + k;
            const bool v2 = (k + 16) < NK;
            u64 r0 = ALOAD(p0), r1 = ALOAD(p0 + 8), r2 = v2 ? ALOAD(p0 + 16) : 0;
            bool ok0 = ((u16)r0 == want), ok1 = ((u16)r1 == want),
                 ok2 = (!v2) || ((u16)r2 == want);
            long guard = 0;
            while (!__all(ok0 && ok1 && ok2) && guard < (1L << 18)) {
                if (!ok0) { r0 = ALOAD(p0);      ok0 = ((u16)r0 == want); }
                if (!ok1) { r1 = ALOAD(p0 + 8);  ok1 = ((u16)r1 == want); }
                if (!ok2) { r2 = ALOAD(p0 + 16); ok2 = ((u16)r2 == want); }
                ++guard;
            }
            u16* dst = sm_t + row * AROW16 + j * 64;
            int db = 3 * k;
            dst[db] = (u16)(r0 >> 16); dst[db + 1] = (u16)(r0 >> 32); dst[db + 2] = (u16)(r0 >> 48);
            db = 3 * (k + 8);
            dst[db] = (u16)(r1 >> 16); dst[db + 1] = (u16)(r1 >> 32); dst[db + 2] = (u16)(r1 >> 48);
            if (v2) {
                db = 3 * (k + 16);
                dst[db] = (u16)(r2 >> 16);
                if (db + 1 < DS) dst[db + 1] = (u16)(r2 >> 32);
                if (db + 2 < DS) dst[db + 2] = (u16)(r2 >> 48);
            }
        }
        __syncthreads();  // A: tile complete

        // ---- gate GEMM: 192 rows x K=512, 4 independent accumulators ----
        const u16* afb = sm_t + (nl & 7) * AROW16 + quad * 8;
        f4 a0 = {0,0,0,0}, a1 = {0,0,0,0}, a2 = {0,0,0,0}, a3 = {0,0,0,0};
#pragma unroll
        for (int kb = 0; kb < 4; ++kb) {
            a0 = __builtin_amdgcn_mfma_f32_16x16x32_bf16(*(const bf8*)(afb + kb * 32),        bfrag[kb],      a0, 0, 0, 0);
            a1 = __builtin_amdgcn_mfma_f32_16x16x32_bf16(*(const bf8*)(afb + (kb + 4) * 32),  bfrag[kb + 4],  a1, 0, 0, 0);
            a2 = __builtin_amdgcn_mfma_f32_16x16x32_bf16(*(const bf8*)(afb + (kb + 8) * 32),  bfrag[kb + 8],  a2, 0, 0, 0);
            a3 = __builtin_amdgcn_mfma_f32_16x16x32_bf16(*(const bf8*)(afb + (kb + 12) * 32), bfrag[kb + 12], a3, 0, 0, 0);
        }
        f4 acc = (a0 + a1) + (a2 + a3);
        if (quad < 2) {
#pragma unroll
            for (int r = 0; r < 4; ++r) ghT[quad * 4 + r][gl] = acc[r];
        }
        __syncthreads();  // B: ghT complete

        // ---- waves 0-7: gate update (1 dim/lane) + publish ----
        if (wave < BT) {
            const int d = lane;
            const float* grow = &ghT[wave][0];
            float rr = sigm(bias_r[d] + grow[d]);
            float zg = sigm(bias_z[d] + grow[64 + d]);
            float nn = tanh_(gin_[d] + rr * (bhn_[d] + grow[128 + d]));
            float h  = (1.f - zg) * nn + zg * hprev_reg;
            hprev_reg = h;
            hpack[wave][d] = f2bf(h);
            const u16 sq = (u16)(base + t);
            if (lane < NK) {
                u16 b0 = hpack[wave][3 * lane], b1 = hpack[wave][3 * lane + 1],
                    b2 = hpack[wave][3 * lane + 2];
                u64 rec = (u64)sq | ((u64)b0 << 16) | ((u64)b1 << 32) | ((u64)b2 << 48);
                ASTORE(&g_ring2[sc][g][s][wave][lane], rec);
            }
        }

        // ---- waves 8-11: projection out[:,tau,:] from sm_t (h(tau+1)=h(t-1)) ----
        // sm16 dbuf: step t+1 stages the OTHER buffer -> no protective barrier.
        const int tau = t - 2;
        if (tau >= 0 && ((tau & 7) == s) && wave >= 8) {
            const int e  = (wave - 8) * 16 + nl;
            const int ec = (e < ENC) ? e : (ENC - 1);
            const u16* wrow = sOutW + ec * OWS + quad * 8;
            f4 accp = {0.f, 0.f, 0.f, 0.f};
#pragma unroll
            for (int kb = 0; kb < 16; ++kb) {
                bf8 av = *(const bf8*)(afb + kb * 32);
                bf8 wv = *(const bf8*)(wrow + kb * 32);
                accp = __builtin_amdgcn_mfma_f32_16x16x32_bf16(av, wv, accp, 0, 0, 0);
            }
            if (quad < 2 && e < ENC) {
                float ob = sOutB[e];
#pragma unroll
                for (int r = 0; r < 4; ++r) {
                    int m = quad * 4 + r;
                    out[(row0 + m) * (OUT_T * ENC) + tau * ENC + e] = accp[r] + ob;
                }
            }
        }
    }

    // ---- tail: tau=255 uses h(256) (slot 0, seq base+256); s==7 projects ----
    if (s == 7) {
        const u16 want = (u16)(base + WIN_);
        u16* sm_t = sm16[1];   // step 256 used buf0; tail stages buf1
        if (wave < BT)
            sm_t[wave * AROW16 + d0 + lane] = f2bf(hprev_reg);
        if (wave >= 1 && wave < 8) {
            const int j = (s + wave) & 7;
            const u64* rb = &g_ring2[0][g][j][0][0];
            const int row = lane >> 3, k = lane & 7;
            {
                const u64* pp = rb + 7 * NKP + 21;
                long guard = 0;
                while ((u16)ALOAD(pp) != want && guard < (1L << 18)) ++guard;
            }
            const u64* p0 = rb + row * NKP + k;
            const bool v2 = (k + 16) < NK;
            u64 r0 = ALOAD(p0), r1 = ALOAD(p0 + 8), r2 = v2 ? ALOAD(p0 + 16) : 0;
            bool ok0 = ((u16)r0 == want), ok1 = ((u16)r1 == want),
                 ok2 = (!v2) || ((u16)r2 == want);
            long guard = 0;
            while (!__all(ok0 && ok1 && ok2) && guard < (1L << 18)) {
                if (!ok0) { r0 = ALOAD(p0);      ok0 = ((u16)r0 == want); }
                if (!ok1) { r1 = ALOAD(p0 + 8);  ok1 = ((u16)r1 == want); }
                if (!ok2) { r2 = ALOAD(p0 + 16); ok2 = ((u16)r2 == want); }
                ++guard;
            }
            u16* dst = sm_t + row * AROW16 + j * 64;
            int db = 3 * k;
            dst[db] = (u16)(r0 >> 16); dst[db + 1] = (u16)(r0 >> 32); dst[db + 2] = (u16)(r0 >> 48);
            db = 3 * (k + 8);
            dst[db] = (u16)(r1 >> 16); dst[db + 1] = (u16)(r1 >> 32); dst[db + 2] = (u16)(r1 >> 48);
            if (v2) {
                db = 3 * (k + 16);
                dst[db] = (u16)(r2 >> 16);
                if (db + 1 < DS) dst[db + 1] = (u16)(r2 >> 32);
                if (db + 2 < DS) dst[db + 2] = (u16)(r2 >> 48);
            }
        }
        __syncthreads();
        if (wave >= 8) {
            const u16* afb = sm_t + (nl & 7) * AROW16 + quad * 8;
            const int e  = (wave - 8) * 16 + nl;
            const int ec = (e < ENC) ? e : (ENC - 1);
            const u16* wrow = sOutW + ec * OWS + quad * 8;
            f4 accp = {0.f, 0.f, 0.f, 0.f};
#pragma unroll
            for (int kb = 0; kb < 16; ++kb) {
                bf8 av = *(const bf8*)(afb + kb * 32);
                bf8 wv = *(const bf8*)(wrow + kb * 32);
                accp = __builtin_amdgcn_mfma_f32_16x16x32_bf16(av, wv, accp, 0, 0, 0);
            }
            if (quad < 2 && e < ENC) {
                float ob = sOutB[e];
#pragma unroll
                for (int r = 0; r < 4; ++r) {
                    int m = quad * 4 + r;
                    out[(row0 + m) * (OUT_T * ENC) + 255 * ENC + e] = accp[r] + ob;
                }
            }
        }
    }

    // bump own launch counter (next launch's base)
    if (tid == 0) ASTORE(lc_own, sh_lc + 1ULL);
}

extern "C" void kernel_launch(void* const* d_in, const int* in_sizes, int n_in,
                              void* d_out, int out_size, void* d_ws, size_t ws_size,
                              hipStream_t stream) {
    const float* z    = (const float*)d_in[0];
    const float* hpw  = (const float*)d_in[1];
    const float* hpb  = (const float*)d_in[2];
    // d_in[3] = w_ih: unused by the reference (input gates are pure biases)
    const float* whh  = (const float*)d_in[4];
    const float* bih  = (const float*)d_in[5];
    const float* bhh  = (const float*)d_in[6];
    const float* outw = (const float*)d_in[7];
    const float* outb = (const float*)d_in[8];
    float* out = (float*)d_out;

    (void)d_ws; (void)ws_size;  // scratch lives in module .bss
    gru_fused<<<dim3(256), dim3(TPB), 0, stream>>>(
        z, hpw, hpb, whh, bih, bhh, outw, outb, out);
}

// Round 13
// 697.494 us; speedup vs baseline: 1.3206x; 1.0758x over previous
//
#include <hip/hip_runtime.h>

#define DM     512
#define LAT    128
#define WIN_   256
#define ENC    55
#define GB     32        // batch groups
#define BT     8         // batch rows per group
#define DS     64        // h-dims per slice
#define TPB    768       // 12 waves
#define OUT_T  256
#define AROW16 528       // u16 per sm16 row (512 data + 16 pad)
#define GHS    200       // ghT row stride in floats
#define OWS    520       // sOutW row stride in u16
#define NK     22        // records per (row, slice): ceil(64/3)
#define NKP    24        // padded record slots

typedef __attribute__((ext_vector_type(8))) short bf8;
typedef __attribute__((ext_vector_type(4))) float f4;
typedef unsigned long long u64;
typedef unsigned short u16;

// .bss scratch: zero at load, not poisoned by the harness.
// Record u64 = [seq16 | bf16 d0 | bf16 d1 | bf16 d2] — single-copy atomic:
// seq and data always consistent. Producers fire-and-forget.
// Consumers poll ONE broadcast line, then fetch-once + validate + retry
// stragglers. (R8/R10: payload-polling floods the MALL; R11: sc0 scope-
// lowering reads stale L1 — agent-scope atomics are the only safe path.)
__device__ __align__(128) u64 g_ring2[2][GB][8][BT][NKP];  // ~786 KB
__device__ __align__(128) u64 g_lcnt[GB * 8 * 16];         // per-(g,s) launch count

__device__ __forceinline__ u16 f2bf(float f) {
    union { float f; unsigned int i; } v; v.f = f;
    unsigned int r = v.i + 0x7fffu + ((v.i >> 16) & 1u);
    return (u16)(r >> 16);
}
__device__ __forceinline__ float sigm(float x) { return 1.f / (1.f + __expf(-x)); }
__device__ __forceinline__ float tanh_(float x) {
    x = fminf(x, 40.f);
    float e = __expf(2.f * x);
    return (e - 1.f) / (e + 1.f);
}
#define ALOAD(p)     __hip_atomic_load((p),      __ATOMIC_RELAXED, __HIP_MEMORY_SCOPE_AGENT)
#define ASTORE(p, v) __hip_atomic_store((p), (v), __ATOMIC_RELAXED, __HIP_MEMORY_SCOPE_AGENT)

// Persistent fused GRU+projection. 256 blocks = 32 batch-groups x 8 d-slices.
// Per step: waves 0-7 stage own slice + poll/fetch one remote slice; all 12
// waves gate GEMM (16 MFMA) vs resident w_hh fragments; waves 0-7 gate math
// (1 dim/lane) -> pack records via LDS -> fire-and-forget publish;
// waves 8-11 projection vs LDS-resident bf16 out_w (1-in-8 steps per block).
// base = lc*512 + 1 (seq never 0 -> virgin .bss can't validate; no aliasing).
__global__ __launch_bounds__(TPB, 3) void gru_fused(
    const float* __restrict__ z,    // [256][128]
    const float* __restrict__ hpw,  // [512][128]
    const float* __restrict__ hpb,  // [512]
    const float* __restrict__ whh,  // [1536][512]
    const float* __restrict__ bih,  // [1536]
    const float* __restrict__ bhh,  // [1536]
    const float* __restrict__ outw, // [55][512]
    const float* __restrict__ outb, // [55]
    float* __restrict__ out)        // [256][256][55] fp32
{
    const int blk  = blockIdx.x;
    const int g    = blk & (GB - 1);
    const int s    = blk >> 5;
    const int d0   = s * DS;
    const int row0 = g * BT;
    const int tid  = threadIdx.x;
    const int wave = tid >> 6;
    const int lane = tid & 63;
    const int quad = lane >> 4;
    const int nl   = lane & 15;

    __shared__ __align__(16) u16 sm16[BT * AROW16];   // staged h(t-1) bf16
    __shared__ __align__(16) float ghT[BT][GHS];      // [batch][gate*64+dim]
    __shared__ float bias_r[DS], bias_z[DS], gin_[DS], bhn_[DS];
    __shared__ __align__(16) u16 hpack[BT][66];       // bf16 h(t) rows + pad
    __shared__ __align__(16) u16 sOutW[ENC * OWS];    // bf16 out_w, padded
    __shared__ float sOutB[64];
    __shared__ u64 sh_lc;

    u64* lc_own = g_lcnt + (u64)(g * 8 + s) * 16;
    if (tid == 0) sh_lc = ALOAD(lc_own);

    if (tid < DS) {
        int dg = d0 + tid;
        bias_r[tid] = bih[dg]       + bhh[dg];
        bias_z[tid] = bih[512 + dg] + bhh[512 + dg];
        gin_[tid]   = bih[1024 + dg];
        bhn_[tid]   = bhh[1024 + dg];
    }
    if (tid < ENC) sOutB[tid] = outb[tid];
    for (int i = tid; i < ENC * DM; i += TPB)
        sOutW[(i >> 9) * OWS + (i & 511)] = f2bf(outw[i]);

    // Resident w_hh B-fragments: this wave's 16 gate rows x K=512.
    const int gl   = wave * 16 + nl;
    const int sel  = gl >> 6;
    const int jrow = sel * 512 + d0 + (gl & 63);
    bf8 bfrag[16];
#pragma unroll
    for (int kb = 0; kb < 16; ++kb) {
        const float* wp = whh + jrow * DM + kb * 32 + quad * 8;
        bf8 v;
#pragma unroll
        for (int j = 0; j < 8; ++j) v[j] = (short)f2bf(wp[j]);
        bfrag[kb] = v;
    }
    __syncthreads();  // sh_lc, biases, sOutW ready

    const u64 base = sh_lc * 512ULL + 1ULL;   // seq never 0 (virgin .bss)
    float hprev_reg = 0.f;                    // waves 0-7: h[row=wave][dim=lane]

    // h0 = tanh(z @ hpw^T + hpb): wave w lane d computes its own element
    if (wave < BT) {
        float acc = hpb[d0 + lane];
        const float* zr = z + (row0 + wave) * LAT;
        const float* wr = hpw + (d0 + lane) * LAT;
#pragma unroll 8
        for (int k = 0; k < LAT; ++k) acc += zr[k] * wr[k];
        hprev_reg = tanh_(acc);
        if (lane < 2) hpack[wave][64 + lane] = 0;   // zero record pads once
        hpack[wave][lane] = f2bf(hprev_reg);
        const u16 sq = (u16)base;
        if (lane < NK) {
            u16 b0 = hpack[wave][3 * lane], b1 = hpack[wave][3 * lane + 1],
                b2 = hpack[wave][3 * lane + 2];
            u64 rec = (u64)sq | ((u64)b0 << 16) | ((u64)b1 << 32) | ((u64)b2 << 48);
            ASTORE(&g_ring2[0][g][s][wave][lane], rec);
        }
    }

    const u16* afrag_base = sm16 + (nl & 7) * AROW16;

    for (int t = 1; t <= WIN_; ++t) {
        const int sp = (t - 1) & 1, sc = t & 1;
        const u16 want = (u16)(base + t - 1);

        // ---- stage h(t-1) into sm16 ----
        if (wave < BT)
            sm16[wave * AROW16 + d0 + lane] = f2bf(hprev_reg);  // own slice
        if (wave >= 1 && wave < 8) {
            const int j = (s + wave) & 7;
            const u64* rb = &g_ring2[sp][g][j][0][0];
            const int row = lane >> 3, k = lane & 7;
            // cheap poll: one broadcast address (late-issued record)
            {
                const u64* pp = rb + 7 * NKP + 21;
                long guard = 0;
                while ((u16)ALOAD(pp) != want && guard < (1L << 18)) ++guard;
            }
            // fetch once + validate + retry stragglers
            const u64* p0 = rb + row * NKP + k;
            const bool v2 = (k + 16) < NK;
            u64 r0 = ALOAD(p0), r1 = ALOAD(p0 + 8), r2 = v2 ? ALOAD(p0 + 16) : 0;
            bool ok0 = ((u16)r0 == want), ok1 = ((u16)r1 == want),
                 ok2 = (!v2) || ((u16)r2 == want);
            long guard = 0;
            while (!__all(ok0 && ok1 && ok2) && guard < (1L << 18)) {
                if (!ok0) { r0 = ALOAD(p0);      ok0 = ((u16)r0 == want); }
                if (!ok1) { r1 = ALOAD(p0 + 8);  ok1 = ((u16)r1 == want); }
                if (!ok2) { r2 = ALOAD(p0 + 16); ok2 = ((u16)r2 == want); }
                ++guard;
            }
            u16* dst = sm16 + row * AROW16 + j * 64;
            int db = 3 * k;
            dst[db] = (u16)(r0 >> 16); dst[db + 1] = (u16)(r0 >> 32); dst[db + 2] = (u16)(r0 >> 48);
            db = 3 * (k + 8);
            dst[db] = (u16)(r1 >> 16); dst[db + 1] = (u16)(r1 >> 32); dst[db + 2] = (u16)(r1 >> 48);
            if (v2) {
                db = 3 * (k + 16);
                dst[db] = (u16)(r2 >> 16);
                if (db + 1 < DS) dst[db + 1] = (u16)(r2 >> 32);
                if (db + 2 < DS) dst[db + 2] = (u16)(r2 >> 48);
            }
        }
        __syncthreads();  // A: tile complete

        // ---- gate GEMM: 192 rows x K=512 ----
        f4 acc = {0.f, 0.f, 0.f, 0.f};
#pragma unroll
        for (int kb = 0; kb < 16; ++kb) {
            bf8 av = *(const bf8*)(afrag_base + quad * 8 + kb * 32);
            acc = __builtin_amdgcn_mfma_f32_16x16x32_bf16(av, bfrag[kb], acc, 0, 0, 0);
        }
        if (quad < 2) {
#pragma unroll
            for (int r = 0; r < 4; ++r) ghT[quad * 4 + r][gl] = acc[r];
        }
        __syncthreads();  // B: ghT complete

        // ---- waves 0-7: gate update (1 dim/lane) + publish ----
        if (wave < BT) {
            const int d = lane;
            const float* grow = &ghT[wave][0];
            float rr = sigm(bias_r[d] + grow[d]);
            float zg = sigm(bias_z[d] + grow[64 + d]);
            float nn = tanh_(gin_[d] + rr * (bhn_[d] + grow[128 + d]));
            float h  = (1.f - zg) * nn + zg * hprev_reg;
            hprev_reg = h;
            hpack[wave][d] = f2bf(h);
            const u16 sq = (u16)(base + t);
            if (lane < NK) {   // same-wave LDS write->read: lgkmcnt-ordered
                u16 b0 = hpack[wave][3 * lane], b1 = hpack[wave][3 * lane + 1],
                    b2 = hpack[wave][3 * lane + 2];
                u64 rec = (u64)sq | ((u64)b0 << 16) | ((u64)b1 << 32) | ((u64)b2 << 48);
                ASTORE(&g_ring2[sc][g][s][wave][lane], rec);
            }
        }

        // ---- waves 8-11: projection out[:,tau,:] from sm16 (h(tau+1)=h(t-1)) ----
        const int tau = t - 2;
        const bool proj = (tau >= 0) && ((tau & 7) == s);
        if (proj && wave >= 8) {
            const int e  = (wave - 8) * 16 + nl;
            const int ec = (e < ENC) ? e : (ENC - 1);
            const u16* wrow = sOutW + ec * OWS + quad * 8;
            f4 accp = {0.f, 0.f, 0.f, 0.f};
#pragma unroll
            for (int kb = 0; kb < 16; ++kb) {
                bf8 av = *(const bf8*)(afrag_base + quad * 8 + kb * 32);
                bf8 wv = *(const bf8*)(wrow + kb * 32);
                accp = __builtin_amdgcn_mfma_f32_16x16x32_bf16(av, wv, accp, 0, 0, 0);
            }
            if (quad < 2 && e < ENC) {
                float ob = sOutB[e];
#pragma unroll
                for (int r = 0; r < 4; ++r) {
                    int m = quad * 4 + r;
                    out[(row0 + m) * (OUT_T * ENC) + tau * ENC + e] = accp[r] + ob;
                }
            }
        }
        if (proj) __syncthreads();  // C: protect sm16 before next stage overwrite
    }

    // ---- tail: tau=255 uses h(256) (slot 0, seq base+256); s==7 projects ----
    if (s == 7) {
        const u16 want = (u16)(base + WIN_);
        if (wave < BT)
            sm16[wave * AROW16 + d0 + lane] = f2bf(hprev_reg);
        if (wave >= 1 && wave < 8) {
            const int j = (s + wave) & 7;
            const u64* rb = &g_ring2[0][g][j][0][0];
            const int row = lane >> 3, k = lane & 7;
            {
                const u64* pp = rb + 7 * NKP + 21;
                long guard = 0;
                while ((u16)ALOAD(pp) != want && guard < (1L << 18)) ++guard;
            }
            const u64* p0 = rb + row * NKP + k;
            const bool v2 = (k + 16) < NK;
            u64 r0 = ALOAD(p0), r1 = ALOAD(p0 + 8), r2 = v2 ? ALOAD(p0 + 16) : 0;
            bool ok0 = ((u16)r0 == want), ok1 = ((u16)r1 == want),
                 ok2 = (!v2) || ((u16)r2 == want);
            long guard = 0;
            while (!__all(ok0 && ok1 && ok2) && guard < (1L << 18)) {
                if (!ok0) { r0 = ALOAD(p0);      ok0 = ((u16)r0 == want); }
                if (!ok1) { r1 = ALOAD(p0 + 8);  ok1 = ((u16)r1 == want); }
                if (!ok2) { r2 = ALOAD(p0 + 16); ok2 = ((u16)r2 == want); }
                ++guard;
            }
            u16* dst = sm16 + row * AROW16 + j * 64;
            int db = 3 * k;
            dst[db] = (u16)(r0 >> 16); dst[db + 1] = (u16)(r0 >> 32); dst[db + 2] = (u16)(r0 >> 48);
            db = 3 * (k + 8);
            dst[db] = (u16)(r1 >> 16); dst[db + 1] = (u16)(r1 >> 32); dst[db + 2] = (u16)(r1 >> 48);
            if (v2) {
                db = 3 * (k + 16);
                dst[db] = (u16)(r2 >> 16);
                if (db + 1 < DS) dst[db + 1] = (u16)(r2 >> 32);
                if (db + 2 < DS) dst[db + 2] = (u16)(r2 >> 48);
            }
        }
        __syncthreads();
        if (wave >= 8) {
            const int e  = (wave - 8) * 16 + nl;
            const int ec = (e < ENC) ? e : (ENC - 1);
            const u16* wrow = sOutW + ec * OWS + quad * 8;
            f4 accp = {0.f, 0.f, 0.f, 0.f};
#pragma unroll
            for (int kb = 0; kb < 16; ++kb) {
                bf8 av = *(const bf8*)(afrag_base + quad * 8 + kb * 32);
                bf8 wv = *(const bf8*)(wrow + kb * 32);
                accp = __builtin_amdgcn_mfma_f32_16x16x32_bf16(av, wv, accp, 0, 0, 0);
            }
            if (quad < 2 && e < ENC) {
                float ob = sOutB[e];
#pragma unroll
                for (int r = 0; r < 4; ++r) {
                    int m = quad * 4 + r;
                    out[(row0 + m) * (OUT_T * ENC) + 255 * ENC + e] = accp[r] + ob;
                }
            }
        }
    }

    // bump own launch counter (next launch's base)
    if (tid == 0) ASTORE(lc_own, sh_lc + 1ULL);
}

extern "C" void kernel_launch(void* const* d_in, const int* in_sizes, int n_in,
                              void* d_out, int out_size, void* d_ws, size_t ws_size,
                              hipStream_t stream) {
    const float* z    = (const float*)d_in[0];
    const float* hpw  = (const float*)d_in[1];
    const float* hpb  = (const float*)d_in[2];
    // d_in[3] = w_ih: unused by the reference (input gates are pure biases)
    const float* whh  = (const float*)d_in[4];
    const float* bih  = (const float*)d_in[5];
    const float* bhh  = (const float*)d_in[6];
    const float* outw = (const float*)d_in[7];
    const float* outb = (const float*)d_in[8];
    float* out = (float*)d_out;

    (void)d_ws; (void)ws_size;  // scratch lives in module .bss
    gru_fused<<<dim3(256), dim3(TPB), 0, stream>>>(
        z, hpw, hpb, whh, bih, bhh, outw, outb, out);
}